// Round 3
// baseline (826.192 us; speedup 1.0000x reference)
//
#include <hip/hip_runtime.h>
#include <hip/hip_bf16.h>
#include <hip/hip_cooperative_groups.h>

namespace cg = cooperative_groups;

// GraphFeatureExtractor: B=64, N=64, T=16, D=512
// out = person_features with [:, :, 15, :] replaced by 2-layer ST-GCN result.
//
// Round 5: single persistent cooperative kernel (512 blocks = 2/CU), phases
// separated by grid.sync(). Copy of the 128 MiB bulk is a work-stealing pool
// consumed by whichever blocks are idle in each phase -> copy BW overlaps
// compute on every CU, and the 4 inter-kernel drain barriers disappear.
// Phase-4 copy skips t=15 rows (k_norm writes them concurrently).
// Fallback to the verified 6-kernel chain if cooperative launch is rejected.

typedef __attribute__((ext_vector_type(8))) short short8;
typedef __attribute__((ext_vector_type(4))) float v4f;

#define DIST_THRESH 150.0f
#define ROW_EPS 1e-6f
#define BN_EPS 1e-5f

__device__ __forceinline__ ushort f2bf(float f) {
  union { __hip_bfloat16 h; ushort u; } cv;
  cv.h = __float2bfloat16(f);
  return cv.u;
}

// ---------------- shared-memory layouts (union'd in the fused kernel) -------
struct AggShared {
  float Xs[64][128];   // 32 KB
  float As[64][64];    // 16 KB
  float cxs[64], cys[64];
  float scaleS[128], shiftS[128];
  float rsum[64][4];
  float invr[64];
};                      // ~50.8 KB
struct GemmShared {
  ushort Zs[64 * 40];  // pad 32->40
  ushort Ws[64 * 40];
  float redS[4][64], redQ[4][64];
};                      // ~12.3 KB
union ShU { AggShared a; GemmShared g; };

// ---------------- copy chunk: 64 lanes x 4 float4 = 4 KB (2 rows of 512 f) --
// skipT15: drop stores of the odd row (it is a t=15 row when (c&7)==7).
__device__ __forceinline__ void copy_chunk(const float4* __restrict__ in,
                                           float4* __restrict__ out,
                                           int c, int lane, bool skipT15) {
  size_t base = (size_t)c * 256 + lane;
  float4 r0 = in[base];
  float4 r1 = in[base + 64];
  float4 r2 = in[base + 128];
  float4 r3 = in[base + 192];
  out[base] = r0;
  out[base + 64] = r1;
  if (!skipT15) {       // offsets 128..255 = row 2c+1
    out[base + 128] = r2;
    out[base + 192] = r3;
  }
}

// per-wave work stealing, 8-chunk groups (32 KB/grab -> ~1K atomics/phase)
__device__ __forceinline__ void steal_copy(const float4* __restrict__ in,
                                           float4* __restrict__ out,
                                           int* __restrict__ ctr,
                                           int base, int ngroups, int lane,
                                           bool p4) {
  for (;;) {
    int i;
    if (lane == 0) i = atomicAdd(ctr, 1);
    i = __shfl(i, 0);
    if (i >= ngroups) break;
#pragma unroll
    for (int k = 0; k < 8; ++k) {
      int c = base + i * 8 + k;
      copy_chunk(in, out, c, lane, p4 && ((c & 7) == 7));
    }
  }
}

// ---------------- weight -> bf16 (float4 granular) --------------------------
__device__ __forceinline__ void prep_unit(int i4, const float* __restrict__ w1,
                                          const float* __restrict__ w2,
                                          ushort* __restrict__ wb) {
  float4 v = (i4 < 65536) ? *(const float4*)&w1[(size_t)i4 * 4]
                          : *(const float4*)&w2[(size_t)(i4 - 65536) * 4];
  ushort4 o;
  o.x = f2bf(v.x);
  o.y = f2bf(v.y);
  o.z = f2bf(v.z);
  o.w = f2bf(v.w);
  *(ushort4*)&wb[(size_t)i4 * 4] = o;
}

// ---------------- aggregation unit (verified body, u = 0..255) --------------
// Z[b][m][c] = sum_n A_norm[b][n][m] * X[b][n][c]
__device__ void agg_unit(int u, int t, const float* __restrict__ Xbase,
                         int rowStride, const float* __restrict__ bb,
                         const float* __restrict__ stats,
                         const float* __restrict__ g,
                         const float* __restrict__ beta, int applyBN,
                         ushort* __restrict__ Z, AggShared& S) {
  int b = u >> 2;
  int c0 = (u & 3) << 7;

  if (t < 64) {
    float4 v = *(const float4*)&bb[(size_t)(b * 64 + t) * 4];
    S.cxs[t] = v.x + 0.5f * v.z;
    S.cys[t] = v.y + 0.5f * v.w;
  }
  if (applyBN && t < 32) {
    int c = t * 4;
    float4 sm = *(const float4*)&stats[c0 + c];
    float4 sq = *(const float4*)&stats[512 + c0 + c];
    float4 gg = *(const float4*)&g[c0 + c];
    float4 bt = *(const float4*)&beta[c0 + c];
    const float inv = 1.0f / 4096.0f;
    float mean, var, sc;
    mean = sm.x * inv; var = sq.x * inv - mean * mean; sc = gg.x * rsqrtf(var + BN_EPS);
    S.scaleS[c] = sc; S.shiftS[c] = bt.x - mean * sc;
    mean = sm.y * inv; var = sq.y * inv - mean * mean; sc = gg.y * rsqrtf(var + BN_EPS);
    S.scaleS[c + 1] = sc; S.shiftS[c + 1] = bt.y - mean * sc;
    mean = sm.z * inv; var = sq.z * inv - mean * mean; sc = gg.z * rsqrtf(var + BN_EPS);
    S.scaleS[c + 2] = sc; S.shiftS[c + 2] = bt.z - mean * sc;
    mean = sm.w * inv; var = sq.w * inv - mean * mean; sc = gg.w * rsqrtf(var + BN_EPS);
    S.scaleS[c + 3] = sc; S.shiftS[c + 3] = bt.w - mean * sc;
  }
  __syncthreads();

  // parallel adjacency: thread t owns row an = t>>2, 16-col segment aq = t&3
  int an = t >> 2, aq = t & 3;
  float av[16];
  {
    float mycx = S.cxs[an], mycy = S.cys[an];
    float ps = 0.f;
#pragma unroll
    for (int j = 0; j < 16; ++j) {
      int m = aq * 16 + j;
      float dx = mycx - S.cxs[m], dy = mycy - S.cys[m];
      float d = sqrtf(dx * dx + dy * dy);
      float a = (m == an) ? 1.0f : ((d < DIST_THRESH) ? 1.0f : 0.0f);
      av[j] = a;
      ps += a;
    }
    S.rsum[an][aq] = ps;
  }

  // X tile load (+BN/relu for layer 2) — overlapped with A-build
  const float* xb = Xbase + (size_t)b * 64 * rowStride;
  for (int i = t; i < 2048; i += 256) {  // 64 rows x 32 float4
    int n = i >> 5, c4 = (i & 31) << 2;
    float4 x = *(const float4*)&xb[(size_t)n * rowStride + c0 + c4];
    if (applyBN) {
      x.x = fmaxf(x.x * S.scaleS[c4] + S.shiftS[c4], 0.f);
      x.y = fmaxf(x.y * S.scaleS[c4 + 1] + S.shiftS[c4 + 1], 0.f);
      x.z = fmaxf(x.z * S.scaleS[c4 + 2] + S.shiftS[c4 + 2], 0.f);
      x.w = fmaxf(x.w * S.scaleS[c4 + 3] + S.shiftS[c4 + 3], 0.f);
    }
    *(float4*)&S.Xs[n][c4] = x;
  }
  __syncthreads();

  if (t < 64)
    S.invr[t] = 1.0f / (S.rsum[t][0] + S.rsum[t][1] + S.rsum[t][2] + S.rsum[t][3] + ROW_EPS);
  __syncthreads();

  {
    float iv = S.invr[an];
#pragma unroll
    for (int j = 0; j < 16; ++j) S.As[an][aq * 16 + j] = av[j] * iv;
  }
  __syncthreads();

  int c4 = (t & 31) << 2;   // column group (4 floats)
  int m0 = (t >> 5) << 3;   // 8 output nodes per thread
  float4 acc[8];
#pragma unroll
  for (int i = 0; i < 8; ++i) acc[i] = make_float4(0.f, 0.f, 0.f, 0.f);

  for (int n = 0; n < 64; ++n) {
    float4 x = *(const float4*)&S.Xs[n][c4];
    float4 a0 = *(const float4*)&S.As[n][m0];
    float4 a1 = *(const float4*)&S.As[n][m0 + 4];
    float as[8] = {a0.x, a0.y, a0.z, a0.w, a1.x, a1.y, a1.z, a1.w};
#pragma unroll
    for (int i = 0; i < 8; ++i) {
      acc[i].x = fmaf(as[i], x.x, acc[i].x);
      acc[i].y = fmaf(as[i], x.y, acc[i].y);
      acc[i].z = fmaf(as[i], x.z, acc[i].z);
      acc[i].w = fmaf(as[i], x.w, acc[i].w);
    }
  }

  size_t zbase = (size_t)b * 64 * 512 + c0 + c4;
#pragma unroll
  for (int i = 0; i < 8; ++i) {
    int m = m0 + i;
    ushort4 zz;
    zz.x = f2bf(acc[i].x);
    zz.y = f2bf(acc[i].y);
    zz.z = f2bf(acc[i].z);
    zz.w = f2bf(acc[i].w);
    *(ushort4*)&Z[zbase + (size_t)m * 512] = zz;
  }
  __syncthreads();  // protect LDS before next reuse
}

// ---------------- GEMM unit (verified body, u = 0..511) ---------------------
// Y[r][o] = sum_c Z[r][c]*W[o][c] + bias[o]; 64x64 tile, BK=32, 4 waves
__device__ void gemm_unit(int u, int t, const ushort* __restrict__ Z,
                          const ushort* __restrict__ W,
                          const float* __restrict__ bias,
                          float* __restrict__ Y, float* __restrict__ sum,
                          float* __restrict__ sumsq, GemmShared& S) {
  int r0 = (u >> 3) << 6;  // 64 row tiles
  int o0 = (u & 7) << 6;   // 8 col tiles
  int wv = t >> 6, lane = t & 63;
  int m = lane & 15, q = lane >> 4;

  v4f acc[4];
#pragma unroll
  for (int nf = 0; nf < 4; ++nf) acc[nf] = (v4f){0.f, 0.f, 0.f, 0.f};

  int srow = t >> 2, scg = (t & 3) << 3;  // staging: row 0..63, 8-bf16 groups
  const ushort* zp = &Z[(size_t)(r0 + srow) * 512 + scg];
  const ushort* wp = &W[(size_t)(o0 + srow) * 512 + scg];

  uint4 zv = *(const uint4*)zp;
  uint4 wvv = *(const uint4*)wp;

  for (int ks = 0; ks < 16; ++ks) {
    __syncthreads();
    *(uint4*)&S.Zs[srow * 40 + scg] = zv;
    *(uint4*)&S.Ws[srow * 40 + scg] = wvv;
    __syncthreads();

    if (ks < 15) {  // prefetch next tile
      zv = *(const uint4*)(zp + (ks + 1) * 32);
      wvv = *(const uint4*)(wp + (ks + 1) * 32);
    }

    short8 a = *(const short8*)&S.Zs[(wv * 16 + m) * 40 + q * 8];
#pragma unroll
    for (int nf = 0; nf < 4; ++nf) {
      short8 bfr = *(const short8*)&S.Ws[(nf * 16 + m) * 40 + q * 8];
      acc[nf] = __builtin_amdgcn_mfma_f32_16x16x32_bf16(a, bfr, acc[nf], 0, 0, 0);
    }
  }

#pragma unroll
  for (int nf = 0; nf < 4; ++nf) {
    int col = o0 + nf * 16 + m;
    float bv = bias[col];
    float s = 0.f, s2 = 0.f;
#pragma unroll
    for (int reg = 0; reg < 4; ++reg) {
      int row = r0 + wv * 16 + q * 4 + reg;
      float y = acc[nf][reg] + bv;
      Y[(size_t)row * 512 + col] = y;
      s += y;
      s2 += y * y;
    }
    s += __shfl_xor(s, 16);
    s += __shfl_xor(s, 32);
    s2 += __shfl_xor(s2, 16);
    s2 += __shfl_xor(s2, 32);
    if (q == 0) {
      S.redS[wv][nf * 16 + m] = s;
      S.redQ[wv][nf * 16 + m] = s2;
    }
  }
  __syncthreads();
  if (t < 64) {
    float s = S.redS[0][t] + S.redS[1][t] + S.redS[2][t] + S.redS[3][t];
    float s2 = S.redQ[0][t] + S.redQ[1][t] + S.redQ[2][t] + S.redQ[3][t];
    atomicAdd(&sum[o0 + t], s);
    atomicAdd(&sumsq[o0 + t], s2);
  }
  __syncthreads();  // protect redS/LDS before next unit reuses
}

// ---------------- final BN + relu unit (unit = 0..2047) ---------------------
__device__ __forceinline__ void norm_unit(int unit, int t,
                                          const float* __restrict__ Y,
                                          const float* __restrict__ sum,
                                          const float* __restrict__ sumsq,
                                          const float* __restrict__ g,
                                          const float* __restrict__ beta,
                                          float* __restrict__ out) {
  int idx = unit * 256 + t;
  int o = (idx & 127) << 2;
  int r = idx >> 7;
  float4 y = *(const float4*)&Y[(size_t)r * 512 + o];
  float4 sm = *(const float4*)&sum[o];
  float4 sq = *(const float4*)&sumsq[o];
  float4 gg = *(const float4*)&g[o];
  float4 bb = *(const float4*)&beta[o];
  const float inv = 1.0f / 4096.0f;
  float4 h;
  {
    float mean = sm.x * inv, var = sq.x * inv - mean * mean;
    h.x = fmaxf(gg.x * (y.x - mean) * rsqrtf(var + BN_EPS) + bb.x, 0.f);
  }
  {
    float mean = sm.y * inv, var = sq.y * inv - mean * mean;
    h.y = fmaxf(gg.y * (y.y - mean) * rsqrtf(var + BN_EPS) + bb.y, 0.f);
  }
  {
    float mean = sm.z * inv, var = sq.z * inv - mean * mean;
    h.z = fmaxf(gg.z * (y.z - mean) * rsqrtf(var + BN_EPS) + bb.z, 0.f);
  }
  {
    float mean = sm.w * inv, var = sq.w * inv - mean * mean;
    h.w = fmaxf(gg.w * (y.w - mean) * rsqrtf(var + BN_EPS) + bb.w, 0.f);
  }
  *(float4*)&out[((size_t)r * 16 + 15) * 512 + o] = h;
}

// ---------------- the fused persistent kernel (512 blocks = 2/CU) -----------
// Copy pool in 4KB chunks, total 32768:
//   P0 static: [0,6144) by prep blocks; P1: [6144,14336); P2: [14336,22528);
//   P3: [22528,30720); P4: [30720,32768) with t=15-row skip.
__global__ __launch_bounds__(256, 2) void k_fused(
    const float* __restrict__ pf, const float* __restrict__ bboxes,
    const float* __restrict__ w1, const float* __restrict__ b1,
    const float* __restrict__ g1, const float* __restrict__ be1,
    const float* __restrict__ w2, const float* __restrict__ b2,
    const float* __restrict__ g2, const float* __restrict__ be2,
    float* __restrict__ out, ushort* __restrict__ wb, ushort* __restrict__ Zb,
    float* __restrict__ Yb, float* __restrict__ stats, int* __restrict__ ctr) {
  cg::grid_group grid = cg::this_grid();
  __shared__ ShU sh;
  int bid = blockIdx.x, t = threadIdx.x, lane = t & 63;
  const float4* in4 = (const float4*)pf;
  float4* out4 = (float4*)out;
  float* sum1 = stats;
  float* sq1 = stats + 512;
  float* sum2 = stats + 1024;
  float* sq2 = stats + 1536;

  // ---- P0: agg1 (256 blocks) | weight prep + stats/ctr zero + static copy --
  if (bid < 256) {
    agg_unit(bid, t, pf + 7680, 8192, bboxes, stats, g1, be1, 0, Zb, sh.a);
  } else {
    int pb = bid - 256;
#pragma unroll
    for (int u = 0; u < 2; ++u) prep_unit((pb * 2 + u) * 256 + t, w1, w2, wb);
    if (pb == 0) {
      for (int i = t; i < 512; i += 256)
        ((float4*)stats)[i] = make_float4(0.f, 0.f, 0.f, 0.f);
      if (t < 8) ctr[t] = 0;
    }
    int cbase = pb * 24 + (t >> 6) * 6;  // 256 blocks x 4 waves x 6 chunks
#pragma unroll
    for (int s = 0; s < 6; ++s) copy_chunk(in4, out4, cbase + s, lane, false);
  }
  __threadfence();
  grid.sync();

  // ---- P1: gemm1 (blocks 0..255, 2 units each) | copy-steal ----------------
  if (bid < 256) {
    gemm_unit(bid * 2, t, Zb, wb, b1, Yb, sum1, sq1, sh.g);
    gemm_unit(bid * 2 + 1, t, Zb, wb, b1, Yb, sum1, sq1, sh.g);
  }
  steal_copy(in4, out4, &ctr[1], 6144, 1024, lane, false);
  __threadfence();
  grid.sync();

  // ---- P2: agg2 with BN1 (blocks 0..255) | copy-steal ----------------------
  if (bid < 256) agg_unit(bid, t, Yb, 512, bboxes, stats, g1, be1, 1, Zb, sh.a);
  steal_copy(in4, out4, &ctr[2], 14336, 1024, lane, false);
  __threadfence();
  grid.sync();

  // ---- P3: gemm2 (blocks 0..255, 2 units each) | copy-steal ----------------
  if (bid < 256) {
    gemm_unit(bid * 2, t, Zb, wb + 262144, b2, Yb, sum2, sq2, sh.g);
    gemm_unit(bid * 2 + 1, t, Zb, wb + 262144, b2, Yb, sum2, sq2, sh.g);
  }
  steal_copy(in4, out4, &ctr[3], 22528, 1024, lane, false);
  __threadfence();
  grid.sync();

  // ---- P4: final BN (blocks 256..511, 8 units) | copy-steal (skip t=15) ----
  if (bid >= 256) {
    int pb = bid - 256;
#pragma unroll
    for (int u = 0; u < 8; ++u)
      norm_unit(pb * 8 + u, t, Yb, sum2, sq2, g2, be2, out);
  }
  steal_copy(in4, out4, &ctr[4], 30720, 256, lane, true);
}

// ---------------- fallback chain (if cooperative launch is rejected) --------
__global__ __launch_bounds__(256) void k_copy_prep_fb(const float4* __restrict__ in,
                                                      float4* __restrict__ out,
                                                      const float* __restrict__ w1,
                                                      const float* __restrict__ w2,
                                                      ushort* __restrict__ wb,
                                                      float* __restrict__ stats) {
  int blk = blockIdx.x, t = threadIdx.x;
  if (blk < 8192) {
    size_t base = (size_t)blk * 1024 + t;
    float4 r0 = in[base];
    float4 r1 = in[base + 256];
    float4 r2 = in[base + 512];
    float4 r3 = in[base + 768];
    out[base] = r0;
    out[base + 256] = r1;
    out[base + 512] = r2;
    out[base + 768] = r3;
  } else {
    prep_unit((blk - 8192) * 256 + t, w1, w2, wb);
    if (blk == 8192) {
      for (int i = t; i < 512; i += 256)
        ((float4*)stats)[i] = make_float4(0.f, 0.f, 0.f, 0.f);
    }
  }
}
__global__ __launch_bounds__(256) void k_agg_fb(const float* __restrict__ Xbase,
                                                int rowStride,
                                                const float* __restrict__ bb,
                                                const float* __restrict__ stats,
                                                const float* __restrict__ g,
                                                const float* __restrict__ beta,
                                                int applyBN,
                                                ushort* __restrict__ Z) {
  __shared__ AggShared S;
  agg_unit(blockIdx.x, threadIdx.x, Xbase, rowStride, bb, stats, g, beta, applyBN, Z, S);
}
__global__ __launch_bounds__(256) void k_gemm_fb(const ushort* __restrict__ Z,
                                                 const ushort* __restrict__ W,
                                                 const float* __restrict__ bias,
                                                 float* __restrict__ Y,
                                                 float* __restrict__ sum,
                                                 float* __restrict__ sumsq) {
  __shared__ GemmShared S;
  gemm_unit(blockIdx.x, threadIdx.x, Z, W, bias, Y, sum, sumsq, S);
}
__global__ __launch_bounds__(256) void k_norm_fb(const float* __restrict__ Y,
                                                 const float* __restrict__ sum,
                                                 const float* __restrict__ sumsq,
                                                 const float* __restrict__ g,
                                                 const float* __restrict__ beta,
                                                 float* __restrict__ out) {
  norm_unit(blockIdx.x, threadIdx.x, Y, sum, sumsq, g, beta, out);
}

extern "C" void kernel_launch(void* const* d_in, const int* in_sizes, int n_in,
                              void* d_out, int out_size, void* d_ws, size_t ws_size,
                              hipStream_t stream) {
  const float* pf = (const float*)d_in[0];
  const float* bboxes = (const float*)d_in[1];
  const float* w1 = (const float*)d_in[2];
  const float* b1 = (const float*)d_in[3];
  const float* g1 = (const float*)d_in[4];
  const float* be1 = (const float*)d_in[5];
  const float* w2 = (const float*)d_in[6];
  const float* b2 = (const float*)d_in[7];
  const float* g2 = (const float*)d_in[8];
  const float* be2 = (const float*)d_in[9];
  float* out = (float*)d_out;

  // workspace layout (~13 MB)
  ushort* wb = (ushort*)d_ws;           // 524288 bf16 (w1|w2)
  ushort* Zb = wb + 524288;             // 2097152 bf16 (Z)
  float* Yb = (float*)(Zb + 2097152);   // 2097152 f32 (Y, reused both layers)
  float* stats = Yb + 2097152;          // 2048 f32: [sum1|sq1|sum2|sq2]
  int* ctr = (int*)(stats + 2048);      // 8 ints: steal counters
  float* sum1 = stats;
  float* sq1 = stats + 512;
  float* sum2 = stats + 1024;
  float* sq2 = stats + 1536;

  void* args[16] = {(void*)&pf,  (void*)&bboxes, (void*)&w1,  (void*)&b1,
                    (void*)&g1,  (void*)&be1,    (void*)&w2,  (void*)&b2,
                    (void*)&g2,  (void*)&be2,    (void*)&out, (void*)&wb,
                    (void*)&Zb,  (void*)&Yb,     (void*)&stats, (void*)&ctr};
  hipError_t e = hipLaunchCooperativeKernel((const void*)k_fused, dim3(512),
                                            dim3(256), args, 0, stream);
  if (e != hipSuccess) {
    (void)hipGetLastError();  // clear; fall back to verified multi-kernel chain
    k_copy_prep_fb<<<8704, 256, 0, stream>>>((const float4*)pf, (float4*)out,
                                             w1, w2, wb, stats);
    k_agg_fb<<<256, 256, 0, stream>>>(pf + 7680, 8192, bboxes, stats, g1, be1, 0, Zb);
    k_gemm_fb<<<512, 256, 0, stream>>>(Zb, wb, b1, Yb, sum1, sq1);
    k_agg_fb<<<256, 256, 0, stream>>>(Yb, 512, bboxes, stats, g1, be1, 1, Zb);
    k_gemm_fb<<<512, 256, 0, stream>>>(Zb, wb + 262144, b2, Yb, sum2, sq2);
    k_norm_fb<<<2048, 256, 0, stream>>>(Yb, sum2, sq2, g2, be2, out);
  }
}

// Round 4
// 290.422 us; speedup vs baseline: 2.8448x; 2.8448x over previous
//
#include <hip/hip_runtime.h>
#include <hip/hip_bf16.h>

// GraphFeatureExtractor: B=64, N=64, T=16, D=512
// out = person_features with [:, :, 15, :] replaced by 2-layer ST-GCN result.
//
// Round 6: back to the verified multi-kernel chain (round-2, 280us), dropping
// the cooperative experiment (650us: same-address atomic storm + 2-blocks/CU
// structural occupancy cap). Changes vs round-2:
//   - copy NEVER touches t=15 rows (norm overwrites them): copy unit = one
//     16-row (b,n) group, with a WAVE-UNIFORM skip of row 15 (k=7 maps to
//     row 14 for t<128, row 15 for t>=128) -> dense-copy BW, -16MB traffic,
//     zero copy/norm races.
//   - 8 float4 in flight per thread (was 4): 2x in-flight bytes where the
//     agg kernel's 51KB LDS caps copy-backfill occupancy at 3 blocks/CU.
//   - copy quotas sized by stage occupancy: agg stages 512 groups, gemm
//     stages 896, norm stage (no LDS, full occupancy) 1280. Round-2 split
//     25% per stage regardless of stage BW capability.
//   - all work distribution static; no atomics beyond the verified gemm
//     stats reduction.

typedef __attribute__((ext_vector_type(8))) short short8;
typedef __attribute__((ext_vector_type(4))) float v4f;

#define DIST_THRESH 150.0f
#define ROW_EPS 1e-6f
#define BN_EPS 1e-5f

__device__ __forceinline__ ushort f2bf(float f) {
  union { __hip_bfloat16 h; ushort u; } cv;
  cv.h = __float2bfloat16(f);
  return cv.u;
}

// ---------------- copy unit: one (b,n) group = 16 rows x 512 f = 8 KB -------
// Copies rows t=0..14 only. Group g covers float4 [g*2048, (g+1)*2048).
// Thread t handles idx t + 256k, k=0..7; k=7 is row 14 for t<128 (copied)
// and row 15 for t>=128 (skipped) -- wave-uniform predicate, dense otherwise.
__device__ __forceinline__ void copy_group(const float4* __restrict__ in,
                                           float4* __restrict__ out,
                                           int g, int t) {
  size_t base = (size_t)g * 2048 + t;
  bool last = (t < 128);  // wave-uniform (waves 0-1 true, waves 2-3 false)
  float4 r[8];
#pragma unroll
  for (int k = 0; k < 7; ++k) r[k] = in[base + (size_t)k * 256];
  if (last) r[7] = in[base + 7 * 256];
#pragma unroll
  for (int k = 0; k < 7; ++k) out[base + (size_t)k * 256] = r[k];
  if (last) out[base + 7 * 256] = r[7];
}

// ---------------- weight -> bf16 (float4 granular) --------------------------
__device__ __forceinline__ void prep_unit(int i4, const float* __restrict__ w1,
                                          const float* __restrict__ w2,
                                          ushort* __restrict__ wb) {
  float4 v = (i4 < 65536) ? *(const float4*)&w1[(size_t)i4 * 4]
                          : *(const float4*)&w2[(size_t)(i4 - 65536) * 4];
  ushort4 o;
  o.x = f2bf(v.x);
  o.y = f2bf(v.y);
  o.z = f2bf(v.z);
  o.w = f2bf(v.w);
  *(ushort4*)&wb[(size_t)i4 * 4] = o;
}

// ---------------- aggregation (+inline adjacency, +optional BN/relu on X) ----
// Z[b][m][c] = sum_n A_norm[b][n][m] * X[b][n][c]
// block roles: [0,256) agg; [256,nonCopy) weight-prep (+zero stats);
//              [nonCopy, grid) copy groups starting at copyBase.
__global__ __launch_bounds__(256) void k_agg(const float* __restrict__ Xbase,
                                             int rowStride,
                                             const float* __restrict__ bb,
                                             const float* __restrict__ stats,  // [sum(512)|sumsq(512)]
                                             const float* __restrict__ g,
                                             const float* __restrict__ beta,
                                             int applyBN,
                                             ushort* __restrict__ Z,
                                             const float4* __restrict__ in4,
                                             float4* __restrict__ out4,
                                             int copyBase,
                                             int nonCopy,
                                             const float* __restrict__ w1,
                                             const float* __restrict__ w2,
                                             ushort* __restrict__ wb,
                                             float* __restrict__ statsZ) {
  int id = blockIdx.x;
  int t = threadIdx.x;

  if (id >= nonCopy) {  // copy role (block-uniform branch, before any barrier)
    copy_group(in4, out4, copyBase + (id - nonCopy), t);
    return;
  }
  if (id >= 256) {  // weight prep role (stage 1 only): 2 units per block
    int pb = id - 256;
#pragma unroll
    for (int u = 0; u < 2; ++u) prep_unit((pb * 2 + u) * 256 + t, w1, w2, wb);
    if (pb == 0) {
      for (int i = t; i < 512; i += 256)
        ((float4*)statsZ)[i] = make_float4(0.f, 0.f, 0.f, 0.f);
    }
    return;
  }

  int b = id >> 2;          // 64 batches
  int c0 = (id & 3) << 7;   // 4 column tiles of 128
  __shared__ float Xs[64][128];  // 32 KB
  __shared__ float As[64][64];   // 16 KB  (A_norm[b], [n][m])
  __shared__ float cxs[64], cys[64];
  __shared__ float scaleS[128], shiftS[128];
  __shared__ float rsum[64][4];
  __shared__ float invr[64];

  if (t < 64) {
    float4 v = *(const float4*)&bb[(size_t)(b * 64 + t) * 4];
    cxs[t] = v.x + 0.5f * v.z;
    cys[t] = v.y + 0.5f * v.w;
  }
  if (applyBN && t < 32) {
    int c = t * 4;  // local column in tile
    float4 sm = *(const float4*)&stats[c0 + c];
    float4 sq = *(const float4*)&stats[512 + c0 + c];
    float4 gg = *(const float4*)&g[c0 + c];
    float4 bt = *(const float4*)&beta[c0 + c];
    const float inv = 1.0f / 4096.0f;
    float mean, var, sc;
    mean = sm.x * inv; var = sq.x * inv - mean * mean; sc = gg.x * rsqrtf(var + BN_EPS);
    scaleS[c] = sc; shiftS[c] = bt.x - mean * sc;
    mean = sm.y * inv; var = sq.y * inv - mean * mean; sc = gg.y * rsqrtf(var + BN_EPS);
    scaleS[c + 1] = sc; shiftS[c + 1] = bt.y - mean * sc;
    mean = sm.z * inv; var = sq.z * inv - mean * mean; sc = gg.z * rsqrtf(var + BN_EPS);
    scaleS[c + 2] = sc; shiftS[c + 2] = bt.z - mean * sc;
    mean = sm.w * inv; var = sq.w * inv - mean * mean; sc = gg.w * rsqrtf(var + BN_EPS);
    scaleS[c + 3] = sc; shiftS[c + 3] = bt.w - mean * sc;
  }
  __syncthreads();

  // parallel adjacency: thread t owns row an = t>>2, 16-col segment aq = t&3
  int an = t >> 2, aq = t & 3;
  float av[16];
  {
    float mycx = cxs[an], mycy = cys[an];
    float ps = 0.f;
#pragma unroll
    for (int j = 0; j < 16; ++j) {
      int m = aq * 16 + j;
      float dx = mycx - cxs[m], dy = mycy - cys[m];
      float d = sqrtf(dx * dx + dy * dy);
      float a = (m == an) ? 1.0f : ((d < DIST_THRESH) ? 1.0f : 0.0f);
      av[j] = a;
      ps += a;
    }
    rsum[an][aq] = ps;
  }

  // X tile load (+BN/relu for layer 2) — overlapped with A-build
  const float* xb = Xbase + (size_t)b * 64 * rowStride;
  for (int i = t; i < 2048; i += 256) {  // 64 rows x 32 float4
    int n = i >> 5, c4 = (i & 31) << 2;
    float4 x = *(const float4*)&xb[(size_t)n * rowStride + c0 + c4];
    if (applyBN) {
      x.x = fmaxf(x.x * scaleS[c4] + shiftS[c4], 0.f);
      x.y = fmaxf(x.y * scaleS[c4 + 1] + shiftS[c4 + 1], 0.f);
      x.z = fmaxf(x.z * scaleS[c4 + 2] + shiftS[c4 + 2], 0.f);
      x.w = fmaxf(x.w * scaleS[c4 + 3] + shiftS[c4 + 3], 0.f);
    }
    *(float4*)&Xs[n][c4] = x;
  }
  __syncthreads();

  if (t < 64)
    invr[t] = 1.0f / (rsum[t][0] + rsum[t][1] + rsum[t][2] + rsum[t][3] + ROW_EPS);
  __syncthreads();

  {
    float iv = invr[an];
#pragma unroll
    for (int j = 0; j < 16; ++j) As[an][aq * 16 + j] = av[j] * iv;
  }
  __syncthreads();

  int c4 = (t & 31) << 2;   // column group (4 floats)
  int m0 = (t >> 5) << 3;   // 8 output nodes per thread
  float4 acc[8];
#pragma unroll
  for (int i = 0; i < 8; ++i) acc[i] = make_float4(0.f, 0.f, 0.f, 0.f);

  for (int n = 0; n < 64; ++n) {
    float4 x = *(const float4*)&Xs[n][c4];
    float4 a0 = *(const float4*)&As[n][m0];
    float4 a1 = *(const float4*)&As[n][m0 + 4];
    float as[8] = {a0.x, a0.y, a0.z, a0.w, a1.x, a1.y, a1.z, a1.w};
#pragma unroll
    for (int i = 0; i < 8; ++i) {
      acc[i].x = fmaf(as[i], x.x, acc[i].x);
      acc[i].y = fmaf(as[i], x.y, acc[i].y);
      acc[i].z = fmaf(as[i], x.z, acc[i].z);
      acc[i].w = fmaf(as[i], x.w, acc[i].w);
    }
  }

  size_t zbase = (size_t)b * 64 * 512 + c0 + c4;
#pragma unroll
  for (int i = 0; i < 8; ++i) {
    int m = m0 + i;
    ushort4 zz;
    zz.x = f2bf(acc[i].x);
    zz.y = f2bf(acc[i].y);
    zz.z = f2bf(acc[i].z);
    zz.w = f2bf(acc[i].w);
    *(ushort4*)&Z[zbase + (size_t)m * 512] = zz;
  }
}

// ---------------- GEMM: Y[r][o] = sum_c Z[r][c]*W[o][c] + bias[o] ------------
// tile 64(M) x 64(N), BK=32, 256 threads = 4 waves, each wave 16 rows x 64 cols
// block roles: [0,512) gemm; [512, grid) copy groups starting at copyBase.
__global__ __launch_bounds__(256) void k_gemm(const ushort* __restrict__ Z,
                                              const ushort* __restrict__ W,
                                              const float* __restrict__ bias,
                                              float* __restrict__ Y,
                                              float* __restrict__ sum,
                                              float* __restrict__ sumsq,
                                              const float4* __restrict__ in4,
                                              float4* __restrict__ out4,
                                              int copyBase) {
  int id = blockIdx.x;
  int t = threadIdx.x;
  if (id >= 512) {  // copy role
    copy_group(in4, out4, copyBase + (id - 512), t);
    return;
  }

  __shared__ __align__(16) ushort Zs[64 * 40];  // pad 32->40
  __shared__ __align__(16) ushort Ws[64 * 40];
  __shared__ float redS[4][64], redQ[4][64];

  int r0 = (id >> 3) << 6;  // 64 row tiles
  int o0 = (id & 7) << 6;   // 8 col tiles
  int wv = t >> 6, lane = t & 63;
  int m = lane & 15, q = lane >> 4;

  v4f acc[4];
#pragma unroll
  for (int nf = 0; nf < 4; ++nf) acc[nf] = (v4f){0.f, 0.f, 0.f, 0.f};

  int srow = t >> 2, scg = (t & 3) << 3;  // staging: row 0..63, 8-bf16 groups
  const ushort* zp = &Z[(size_t)(r0 + srow) * 512 + scg];
  const ushort* wp = &W[(size_t)(o0 + srow) * 512 + scg];

  // prefetch first tile
  uint4 zv = *(const uint4*)zp;
  uint4 wvv = *(const uint4*)wp;

  for (int ks = 0; ks < 16; ++ks) {
    __syncthreads();
    *(uint4*)&Zs[srow * 40 + scg] = zv;
    *(uint4*)&Ws[srow * 40 + scg] = wvv;
    __syncthreads();

    if (ks < 15) {  // prefetch next tile; latency hides under ds_read+MFMA
      zv = *(const uint4*)(zp + (ks + 1) * 32);
      wvv = *(const uint4*)(wp + (ks + 1) * 32);
    }

    short8 a = *(const short8*)&Zs[(wv * 16 + m) * 40 + q * 8];
#pragma unroll
    for (int nf = 0; nf < 4; ++nf) {
      short8 bfr = *(const short8*)&Ws[(nf * 16 + m) * 40 + q * 8];
      acc[nf] = __builtin_amdgcn_mfma_f32_16x16x32_bf16(a, bfr, acc[nf], 0, 0, 0);
    }
  }

  // epilogue: bias, store Y fp32, per-column BN partial sums
#pragma unroll
  for (int nf = 0; nf < 4; ++nf) {
    int col = o0 + nf * 16 + m;
    float bv = bias[col];
    float s = 0.f, s2 = 0.f;
#pragma unroll
    for (int reg = 0; reg < 4; ++reg) {
      int row = r0 + wv * 16 + q * 4 + reg;
      float y = acc[nf][reg] + bv;
      Y[(size_t)row * 512 + col] = y;
      s += y;
      s2 += y * y;
    }
    s += __shfl_xor(s, 16);
    s += __shfl_xor(s, 32);
    s2 += __shfl_xor(s2, 16);
    s2 += __shfl_xor(s2, 32);
    if (q == 0) {
      redS[wv][nf * 16 + m] = s;
      redQ[wv][nf * 16 + m] = s2;
    }
  }
  __syncthreads();
  if (t < 64) {
    float s = redS[0][t] + redS[1][t] + redS[2][t] + redS[3][t];
    float s2 = redQ[0][t] + redQ[1][t] + redQ[2][t] + redQ[3][t];
    atomicAdd(&sum[o0 + t], s);
    atomicAdd(&sumsq[o0 + t], s2);
  }
}

// ---------------- final BN + relu -> t=15 slice of d_out ---------------------
// block roles: [0,2048) norm; [2048, grid) copy groups (no LDS -> full occ.)
__global__ __launch_bounds__(256) void k_norm(const float* __restrict__ Y,
                                              const float* __restrict__ sum,
                                              const float* __restrict__ sumsq,
                                              const float* __restrict__ g,
                                              const float* __restrict__ beta,
                                              float* __restrict__ out,
                                              const float4* __restrict__ in4,
                                              float4* __restrict__ out4,
                                              int copyBase) {
  int id = blockIdx.x;
  int t = threadIdx.x;
  if (id >= 2048) {  // copy role (copy never writes t=15 rows -> no race)
    copy_group(in4, out4, copyBase + (id - 2048), t);
    return;
  }
  int idx = id * 256 + t;  // 524288 float4 groups
  int o = (idx & 127) << 2;
  int r = idx >> 7;
  float4 y = *(const float4*)&Y[(size_t)r * 512 + o];
  float4 sm = *(const float4*)&sum[o];
  float4 sq = *(const float4*)&sumsq[o];
  float4 gg = *(const float4*)&g[o];
  float4 bb = *(const float4*)&beta[o];
  const float inv = 1.0f / 4096.0f;
  float4 h;
  {
    float mean = sm.x * inv, var = sq.x * inv - mean * mean;
    h.x = fmaxf(gg.x * (y.x - mean) * rsqrtf(var + BN_EPS) + bb.x, 0.f);
  }
  {
    float mean = sm.y * inv, var = sq.y * inv - mean * mean;
    h.y = fmaxf(gg.y * (y.y - mean) * rsqrtf(var + BN_EPS) + bb.y, 0.f);
  }
  {
    float mean = sm.z * inv, var = sq.z * inv - mean * mean;
    h.z = fmaxf(gg.z * (y.z - mean) * rsqrtf(var + BN_EPS) + bb.z, 0.f);
  }
  {
    float mean = sm.w * inv, var = sq.w * inv - mean * mean;
    h.w = fmaxf(gg.w * (y.w - mean) * rsqrtf(var + BN_EPS) + bb.w, 0.f);
  }
  *(float4*)&out[((size_t)r * 16 + 15) * 512 + o] = h;
}

extern "C" void kernel_launch(void* const* d_in, const int* in_sizes, int n_in,
                              void* d_out, int out_size, void* d_ws, size_t ws_size,
                              hipStream_t stream) {
  const float* pf = (const float*)d_in[0];
  const float* bboxes = (const float*)d_in[1];
  const float* w1 = (const float*)d_in[2];
  const float* b1 = (const float*)d_in[3];
  const float* g1 = (const float*)d_in[4];
  const float* be1 = (const float*)d_in[5];
  const float* w2 = (const float*)d_in[6];
  const float* b2 = (const float*)d_in[7];
  const float* g2 = (const float*)d_in[8];
  const float* be2 = (const float*)d_in[9];
  float* out = (float*)d_out;

  // workspace layout (~13 MB)
  ushort* wb = (ushort*)d_ws;           // 524288 bf16 (w1|w2)
  ushort* Zb = wb + 524288;             // 2097152 bf16 (Z)
  float* Yb = (float*)(Zb + 2097152);   // 2097152 f32 (Y, reused both layers)
  float* stats = Yb + 2097152;          // 2048 f32: [sum1|sq1|sum2|sq2]
  float* sum1 = stats;
  float* sq1 = stats + 512;
  float* sum2 = stats + 1024;
  float* sq2 = stats + 1536;

  const float4* in4 = (const float4*)pf;
  float4* out4 = (float4*)out;

  // copy pool: 4096 groups (one per (b,n), 16 rows each; t=15 never copied).
  // quotas by stage occupancy: agg (51KB LDS, 3/CU) 512; gemm (12KB) 896;
  // norm (no LDS) 1280.  512+896+512+896+1280 = 4096.

  // S1: agg1 (X = pf[:, :, 15, :]) + weight prep + zero stats + copy[0,512)
  k_agg<<<256 + 256 + 512, 256, 0, stream>>>(pf + 7680, 8192, bboxes, stats,
                                             g1, be1, 0, Zb,
                                             in4, out4, 0, 512, w1, w2, wb, stats);
  // S2: gemm1 + copy[512,1408)
  k_gemm<<<512 + 896, 256, 0, stream>>>(Zb, wb, b1, Yb, sum1, sq1,
                                        in4, out4, 512);
  // S3: agg2 (X = BN1(Yb) inline) + copy[1408,1920)
  k_agg<<<256 + 512, 256, 0, stream>>>(Yb, 512, bboxes, stats,
                                       g1, be1, 1, Zb,
                                       in4, out4, 1408, 256, w1, w2, wb, stats);
  // S4: gemm2 + copy[1920,2816)
  k_gemm<<<512 + 896, 256, 0, stream>>>(Zb, wb + 262144, b2, Yb, sum2, sq2,
                                        in4, out4, 1920);
  // S5: norm (t=15 slice) + copy[2816,4096) at full occupancy
  k_norm<<<2048 + 1280, 256, 0, stream>>>(Yb, sum2, sq2, g2, be2, out,
                                          in4, out4, 2816);
}